// Round 6
// baseline (76.502 us; speedup 1.0000x reference)
//
#include <hip/hip_runtime.h>
#include <math.h>

// Problem constants (fixed-shape harness: B=4, L=1024, U=256, H=8, dh=32, td=8)
#define B_DIM 4
#define L_DIM 1024
#define H_DIM 8
#define D_DIM 32
#define TD 8
#define NTILES_TOT 1056       // sum over 16-row q-tiles of k-tile count
#define SCALE 0.17677669529663687f          // 1/sqrt(32)

typedef unsigned short ushort_t;
typedef __attribute__((ext_vector_type(8))) short short8v;
typedef __attribute__((ext_vector_type(4))) float f32x4;

// causal tiling helpers (16-row q-tiles, 32-key k-tiles)
__device__ __forceinline__ int ntiles_of(int qt) { return (qt >> 1) + 1; }
__device__ __forceinline__ int off_of(int qt) {
  int m = qt >> 1;
  return (qt & 1) ? (m + 1) * (m + 1) : m * m + m;
}

__device__ __forceinline__ ushort_t f2bf(float f) {
  unsigned u = __builtin_bit_cast(unsigned, f);
  u += 0x7FFFu + ((u >> 16) & 1u);
  return (ushort_t)(u >> 16);
}
__device__ __forceinline__ float bf2f(ushort_t h) {
  return __builtin_bit_cast(float, ((unsigned)h) << 16);
}
__device__ __forceinline__ short8v pack84(float4 a, float4 b) {
  short8v r;
  r[0] = (short)f2bf(a.x); r[1] = (short)f2bf(a.y);
  r[2] = (short)f2bf(a.z); r[3] = (short)f2bf(a.w);
  r[4] = (short)f2bf(b.x); r[5] = (short)f2bf(b.y);
  r[6] = (short)f2bf(b.z); r[7] = (short)f2bf(b.w);
  return r;
}

// ---------------------------------------------------------------------------
// Kernel 1: WORK = QKV MFMA GEMM (blk < 384) + tk tiles (blk >= 384).
// GEMM: X converted bf16 inline (no X-pack pass); W staged per-k-tile into
// 8KB double-buffered LDS frag layout; writes Qf(prescaled by SCALE)/Kf
// A-frag and Vf B-frag bf16 buffers.
// tk: recomputes its 48 positions' fp64 time-features inline (removes the
// prep dispatch); output tiles in C-frag order, prescaled by SCALE.
// ---------------------------------------------------------------------------
__global__ __launch_bounds__(256) void work_kernel(
    const float* __restrict__ Xq, const float* __restrict__ Xi,
    const float* __restrict__ Wq, const float* __restrict__ Wk,
    const float* __restrict__ Wv, const float* __restrict__ t_in,
    const float* __restrict__ pW1, const float* __restrict__ pb1,
    const float* __restrict__ pW2, const float* __restrict__ pb2,
    const float* __restrict__ sW1, const float* __restrict__ sb1,
    const float* __restrict__ sW2, const float* __restrict__ sb2,
    const float* __restrict__ bW1, const float* __restrict__ bb1,
    const float* __restrict__ bW2, const float* __restrict__ bb2,
    ushort_t* __restrict__ Qf, ushort_t* __restrict__ Kf,
    ushort_t* __restrict__ Vf, float* __restrict__ tkbuf) {
  __shared__ __align__(16) char smem[8192];
  const int blk = blockIdx.x;
  const int tid = threadIdx.x;

  if (blk < 384) {
    // ------------------------- GEMM branch -------------------------
    const int z = blk >> 7;                 // 0..2 (Q,K,V)
    const int rem = blk & 127;
    const int m0 = (rem & 31) * 128;        // 128 rows
    const int n0 = (rem >> 5) * 64;         // 64 cols
    const float* X = (z == 0) ? Xq : Xi;
    const float* W = (z == 0) ? Wq : (z == 1) ? Wk : Wv;
    ushort_t* wl = (ushort_t*)smem;         // [2][4*64*8]
    const int w = tid >> 6, l = tid & 63, lg = l >> 4, lc = l & 15;
    const int wm = w >> 1, wn = w & 1;

    auto stageW = [&](int kt, int buf) {
      ushort_t* wb = wl + buf * 2048;
#pragma unroll
      for (int half = 0; half < 2; ++half) {
        int f = half * 256 + tid;           // 0..511 float4s
        int k = f >> 4;                     // 0..31
        int nc = (f & 15) << 2;             // 0..60
        float4 v4 = *(const float4*)&W[(size_t)(kt * 32 + k) * 256 + n0 + nc];
        float va[4] = {v4.x, v4.y, v4.z, v4.w};
#pragma unroll
        for (int u = 0; u < 4; ++u) {
          int n6 = nc + u;
          wb[(((n6 >> 4) * 4 + (k >> 3)) * 16 + (n6 & 15)) * 8 + (k & 7)] = f2bf(va[u]);
        }
      }
    };

    f32x4 acc[4][2];
#pragma unroll
    for (int mi = 0; mi < 4; ++mi)
#pragma unroll
      for (int ni = 0; ni < 2; ++ni) acc[mi][ni] = (f32x4){0.f, 0.f, 0.f, 0.f};

    stageW(0, 0);
    __syncthreads();
    for (int kt0 = 0; kt0 < 8; ++kt0) {
      if (kt0 < 7) stageW(kt0 + 1, (kt0 + 1) & 1);
      short8v a[4], bfr[2];
#pragma unroll
      for (int mi = 0; mi < 4; ++mi) {
        const float* xp = &X[(size_t)(m0 + (wm * 4 + mi) * 16 + lc) * 256 + kt0 * 32 + lg * 8];
        a[mi] = pack84(*(const float4*)xp, *(const float4*)(xp + 4));
      }
#pragma unroll
      for (int ni = 0; ni < 2; ++ni)
        bfr[ni] = *(const short8v*)&wl[(kt0 & 1) * 2048 + ((wn * 2 + ni) * 64 + l) * 8];
#pragma unroll
      for (int mi = 0; mi < 4; ++mi)
#pragma unroll
        for (int ni = 0; ni < 2; ++ni)
          acc[mi][ni] = __builtin_amdgcn_mfma_f32_16x16x32_bf16(a[mi], bfr[ni], acc[mi][ni], 0, 0, 0);
      __syncthreads();
    }

#pragma unroll
    for (int mi = 0; mi < 4; ++mi) {
#pragma unroll
      for (int ni = 0; ni < 2; ++ni) {
        const int col = n0 + wn * 32 + ni * 16 + lc;
        const int hh = col >> 5, d = col & 31;
#pragma unroll
        for (int r = 0; r < 4; ++r) {
          const int row = m0 + (wm * 4 + mi) * 16 + lg * 4 + r;
          const int bb = row >> 10, lr = row & (L_DIM - 1);
          float v = acc[mi][ni][r];
          if (z == 0) v *= SCALE;           // fold attention scale into Q
          const ushort_t bv = f2bf(v);
          if (z == 2) {
            Vf[(((size_t)(bb * H_DIM + hh) * 32 + (lr >> 5)) * 2 + (d >> 4)) * 512 +
               (((lr >> 3) & 3) * 16 + (d & 15)) * 8 + (lr & 7)] = bv;
          } else {
            ushort_t* of16 = (z == 0) ? Qf : Kf;
            of16[((size_t)((bb * H_DIM + hh) * 64 + (lr >> 4))) * 512 +
                 ((d >> 3) * 16 + (lr & 15)) * 8 + (d & 7)] = bv;
          }
        }
      }
    }
  } else {
    // ------------------------- tk branch -------------------------
    const int lin = blk - 384;              // 0..4223
    const int b = lin / NTILES_TOT;
    const int t1 = lin - b * NTILES_TOT;    // 0..1055
    int m = (int)sqrtf((float)t1 + 1.0f);
    while (m * m + m > t1) --m;
    while ((m + 1) * (m + 1) + (m + 1) <= t1) ++m;
    const int rem = t1 - (m * m + m);
    int qt, kt;
    if (rem <= m) { qt = 2 * m; kt = rem; }
    else          { qt = 2 * m + 1; kt = rem - (m + 1); }
    const int q0 = qt << 4, k0 = kt << 5;

    float* ptq = (float*)(smem);            // [16][8]
    float* qs  = (float*)(smem + 512);
    float* qb  = (float*)(smem + 1024);
    float* ptk = (float*)(smem + 1536);     // [32][9] padded
    float* ks  = (float*)(smem + 2688);
    float* kb  = (float*)(smem + 3840);
    float* trow= (float*)(smem + 4992);
    float* tcol= (float*)(smem + 5056);

    if (tid < 16) trow[tid] = t_in[b * L_DIM + q0 + tid];
    if (tid < 32) tcol[tid] = t_in[b * L_DIM + k0 + tid];
    // inline fp64 time-features for this block's 48 positions (3 MLPs x 8 e)
    for (int s = tid; s < 1152; s += 256) {
      const int z = s / 384;
      const int rm = s - z * 384;
      const int p = rm >> 3, e = rm & 7;
      const int gi = (p < 16) ? (q0 + p) : (k0 + p - 16);
      const double t = (double)t_in[b * L_DIM + gi];
      const float* W1 = (z == 0) ? pW1 : (z == 1) ? sW1 : bW1;
      const float* b1 = (z == 0) ? pb1 : (z == 1) ? sb1 : bb1;
      const float* W2 = (z == 0) ? pW2 : (z == 1) ? sW2 : bW2;
      const float* b2 = (z == 0) ? pb2 : (z == 1) ? sb2 : bb2;
      double acc = (double)b2[e];
#pragma unroll
      for (int d = 0; d < 8; ++d) {
        double hv = t * (double)W1[d] + (double)b1[d];
        hv = hv > 0.0 ? hv : 0.0;
        acc += hv * (double)W2[d * 8 + e];
      }
      acc = acc > 0.0 ? acc : 0.0;
      float val;
      if (z == 0) { double pt = acc * t; val = (float)(pt - floor(pt)); }
      else if (z == 1) val = (float)(acc + 1e-6);
      else val = (float)acc;
      if (p < 16) (z == 0 ? ptq : z == 1 ? qs : qb)[p * 8 + e] = val;
      else        (z == 0 ? ptk : z == 1 ? ks : kb)[(p - 16) * 9 + e] = val;
    }
    __syncthreads();

    float* dst = &tkbuf[(size_t)(b * NTILES_TOT + off_of(qt) + kt) * 512];
#pragma unroll
    for (int pp = 0; pp < 2; ++pp) {
      int idx = tid + (pp << 8);
      int lr2 = (idx >> 2) & 63;
      int r = idx & 3;
      int i = ((lr2 >> 4) << 2) | r;
      int j = ((idx >> 8) << 4) | (lr2 & 15);
      float td2 = trow[i] - tcol[j];
      td2 *= td2;
      float a = 0.f;
#pragma unroll
      for (int d = 0; d < TD; ++d) {
        float sqd = qs[i * 8 + d], skd = ks[j * 9 + d];
        float denom = sqd * sqd + skd * skd;
        float inv = __builtin_amdgcn_rcpf(denom);
        float ee = __expf(-td2 * inv);
        float le = __builtin_amdgcn_sqrtf(2.f * sqd * skd * inv);
        float dq = ptq[i * 8 + d] - ptk[j * 9 + d];
        float ce = __builtin_amdgcn_cosf(dq);   // v_cos: input in revolutions
        a += qb[i * 8 + d] * kb[j * 9 + d] * (le * ee * ce);
      }
      dst[idx] = a * SCALE;                 // fold attention scale into tk
    }
  }
}

// ---------------------------------------------------------------------------
// Kernel 2: ATTENTION (x<16) + ROW-0 fixup (x==16), grid (17, 8, 4).
// Attention: 4 waves x 16 q-rows; K/tk/V frags register-prefetched one
// k-chunk ahead (double-buffered) so L2/L3 latency hides under MFMA+softmax;
// s_setprio(1) around MFMA clusters. Scores = QK' + tk' (pre-scaled).
// ---------------------------------------------------------------------------
struct AFrags {
  short8v k0, k1, k2, k3;
  float4 t0, t1, t2, t3;
  short8v v0, v1, v2, v3;
};

__global__ __launch_bounds__(256) void attn_row0_kernel(
    const ushort_t* __restrict__ Qf, const ushort_t* __restrict__ Kf,
    const ushort_t* __restrict__ Vf, const float* __restrict__ tkbuf,
    const int* __restrict__ imask, float* __restrict__ out) {
  __shared__ __align__(16) ushort_t lds_p[4][1024];  // per-wave P (8 KB)
  __shared__ float p_s[L_DIM];                       // row0 (4 KB)
  __shared__ float qsh[D_DIM];
  __shared__ float red[8][33];
  __shared__ float rtmp[4];

  const int h = blockIdx.y;
  const int b = blockIdx.z;
  const int tid = threadIdx.x;
  const int fb = (b * H_DIM + h) * 64;   // frag-tile base (16-row tiles)
  const int vb = (b * H_DIM + h) * 32;   // V-group base (32-key groups)

  if (blockIdx.x == 16) {
    // ---------------- row-0 path ----------------
    if (tid < D_DIM)
      qsh[tid] = bf2f(Qf[(size_t)fb * 512 + (tid >> 3) * 128 + (tid & 7)]);
    __syncthreads();

    float lmax = -1e30f;
    for (int j = tid; j < L_DIM; j += 256) {
      int i = j & 15;
      float tkv = tkbuf[(size_t)(b * NTILES_TOT + off_of(j >> 4)) * 512 +
                        (((i >> 2) << 6) | (i & 3))];
      const ushort_t* kp = &Kf[(size_t)(fb + (j >> 4)) * 512 + (j & 15) * 8];
      float dot = 0.f;
#pragma unroll
      for (int o = 0; o < 4; ++o) {
        short8v kv = *(const short8v*)&kp[o * 128];
#pragma unroll
        for (int u = 0; u < 8; ++u) dot += qsh[o * 8 + u] * bf2f((ushort_t)kv[u]);
      }
      float sc = dot + tkv;               // both pre-scaled
      p_s[j] = sc;
      lmax = fmaxf(lmax, sc);
    }
#pragma unroll
    for (int o = 1; o < 64; o <<= 1) lmax = fmaxf(lmax, __shfl_xor(lmax, o));
    if ((tid & 63) == 0) rtmp[tid >> 6] = lmax;
    __syncthreads();
    const float bmax = fmaxf(fmaxf(rtmp[0], rtmp[1]), fmaxf(rtmp[2], rtmp[3]));
    __syncthreads();

    float lsumv = 0.f;
    for (int j = tid; j < L_DIM; j += 256) {
      float pv = __expf(p_s[j] - bmax);
      p_s[j] = pv;
      lsumv += pv;
    }
#pragma unroll
    for (int o = 1; o < 64; o <<= 1) lsumv += __shfl_xor(lsumv, o);
    if ((tid & 63) == 0) rtmp[tid >> 6] = lsumv;
    __syncthreads();
    const float bsum = rtmp[0] + rtmp[1] + rtmp[2] + rtmp[3];

    const int g = tid >> 5, d = tid & 31;
    float a = 0.f;
    for (int j = g * 128; j < g * 128 + 128; ++j) {
      float v = bf2f(Vf[(((size_t)(vb + (j >> 5))) * 2 + (d >> 4)) * 512 +
                        (((j >> 3) & 3) * 16 + (d & 15)) * 8 + (j & 7)]);
      a = fmaf(p_s[j], v, a);
    }
    red[g][d] = a;
    __syncthreads();
    if (tid < D_DIM) {
      float acc = 0.f;
#pragma unroll
      for (int gg = 0; gg < 8; ++gg) acc += red[gg][tid];
      float qabs = 0.f;
#pragma unroll
      for (int dd = 0; dd < D_DIM; ++dd) qabs += fabsf(qsh[dd]);
      const float qmv = qabs > 0.f ? 1.f : 0.f;
      out[((size_t)b * L_DIM) * 256 + h * D_DIM + tid] =
          acc * (1.0f / bsum) * qmv * (float)imask[b * L_DIM];
    }
    return;
  }

  // ---------------- attention path ----------------
  const int qc = (b >= 2) ? (int)blockIdx.x : 15 - (int)blockIdx.x;
  const int w = tid >> 6;
  const int l = tid & 63;
  const int lg = l >> 4;
  const int lc = l & 15;
  const int qbase = qc * 64 + w * 16;
  const int qt = qbase >> 4;

  short8v qfrag = *(const short8v*)&Qf[((size_t)(fb + qt)) * 512 + l * 8];
  float qabs_l = 0.f;
#pragma unroll
  for (int j = 0; j < 8; ++j) qabs_l += fabsf(bf2f((ushort_t)qfrag[j]));
  qabs_l += __shfl_xor(qabs_l, 16);
  qabs_l += __shfl_xor(qabs_l, 32);
  const float qm = (qabs_l > 0.f) ? 1.f : 0.f;

  f32x4 O0 = {0.f, 0.f, 0.f, 0.f};
  f32x4 O1 = {0.f, 0.f, 0.f, 0.f};
  float mrow[4] = {-1e30f, -1e30f, -1e30f, -1e30f};
  float lrow[4] = {0.f, 0.f, 0.f, 0.f};
  const float* tk_qt = &tkbuf[(size_t)(b * NTILES_TOT + off_of(qt)) * 512];
  ushort_t* Pw = lds_p[w];

  auto loadf = [&](AFrags& F, int kc) {
    const size_t kb_ = ((size_t)(fb + kc * 4)) * 512 + l * 8;
    F.k0 = *(const short8v*)&Kf[kb_];
    F.k1 = *(const short8v*)&Kf[kb_ + 512];
    F.k2 = *(const short8v*)&Kf[kb_ + 1024];
    F.k3 = *(const short8v*)&Kf[kb_ + 1536];
    const size_t tb_ = (size_t)(kc * 2) * 512 + l * 4;
    F.t0 = *(const float4*)&tk_qt[tb_];
    F.t1 = *(const float4*)&tk_qt[tb_ + 256];
    F.t2 = *(const float4*)&tk_qt[tb_ + 512];
    F.t3 = *(const float4*)&tk_qt[tb_ + 768];
    const size_t vb_ = ((size_t)(vb + kc * 2)) * 1024 + l * 8;
    F.v0 = *(const short8v*)&Vf[vb_];
    F.v1 = *(const short8v*)&Vf[vb_ + 512];
    F.v2 = *(const short8v*)&Vf[vb_ + 1024];
    F.v3 = *(const short8v*)&Vf[vb_ + 1536];
  };

  auto iterate = [&](const AFrags& F, int kc, bool diag) {
    f32x4 z4 = {0.f, 0.f, 0.f, 0.f};
    __builtin_amdgcn_s_setprio(1);
    f32x4 sv0 = __builtin_amdgcn_mfma_f32_16x16x32_bf16(qfrag, F.k0, z4, 0, 0, 0);
    f32x4 sv1 = __builtin_amdgcn_mfma_f32_16x16x32_bf16(qfrag, F.k1, z4, 0, 0, 0);
    f32x4 sv2 = __builtin_amdgcn_mfma_f32_16x16x32_bf16(qfrag, F.k2, z4, 0, 0, 0);
    f32x4 sv3 = __builtin_amdgcn_mfma_f32_16x16x32_bf16(qfrag, F.k3, z4, 0, 0, 0);
    __builtin_amdgcn_s_setprio(0);
    float s[4][4];
    const float* tka[4] = {(const float*)&F.t0, (const float*)&F.t1,
                           (const float*)&F.t2, (const float*)&F.t3};
    const f32x4* svs[4] = {&sv0, &sv1, &sv2, &sv3};
#pragma unroll
    for (int kt = 0; kt < 4; ++kt) {
      const int col = kc * 64 + kt * 16 + lc;
#pragma unroll
      for (int r = 0; r < 4; ++r) {
        float val = (*svs[kt])[r] + tka[kt][r];
        if (diag && col >= qbase + lg * 4 + r) val = -10000.0f;
        s[kt][r] = val;
      }
    }
#pragma unroll
    for (int r = 0; r < 4; ++r) {
      float tmax = fmaxf(fmaxf(s[0][r], s[1][r]), fmaxf(s[2][r], s[3][r]));
      tmax = fmaxf(tmax, __shfl_xor(tmax, 1));
      tmax = fmaxf(tmax, __shfl_xor(tmax, 2));
      tmax = fmaxf(tmax, __shfl_xor(tmax, 4));
      tmax = fmaxf(tmax, __shfl_xor(tmax, 8));
      float mnew = fmaxf(mrow[r], tmax);
      float cf = __expf(mrow[r] - mnew);
      mrow[r] = mnew;
      float p0 = __expf(s[0][r] - mnew);
      float p1 = __expf(s[1][r] - mnew);
      float p2 = __expf(s[2][r] - mnew);
      float p3 = __expf(s[3][r] - mnew);
      float psum = (p0 + p1) + (p2 + p3);
      psum += __shfl_xor(psum, 1);
      psum += __shfl_xor(psum, 2);
      psum += __shfl_xor(psum, 4);
      psum += __shfl_xor(psum, 8);
      lrow[r] = lrow[r] * cf + psum;
      O0[r] *= cf;
      O1[r] *= cf;
      const int pb = ((lc >> 3) << 7) + ((lg * 4 + r) << 3) + (lc & 7);
      Pw[pb] = f2bf(p0);
      Pw[pb + 256] = f2bf(p1);
      Pw[pb + 512] = f2bf(p2);
      Pw[pb + 768] = f2bf(p3);
    }
    short8v pf0 = *(const short8v*)&Pw[l * 8];
    short8v pf1 = *(const short8v*)&Pw[(64 + l) * 8];
    __builtin_amdgcn_s_setprio(1);
    O0 = __builtin_amdgcn_mfma_f32_16x16x32_bf16(pf0, F.v0, O0, 0, 0, 0);
    O1 = __builtin_amdgcn_mfma_f32_16x16x32_bf16(pf0, F.v1, O1, 0, 0, 0);
    O0 = __builtin_amdgcn_mfma_f32_16x16x32_bf16(pf1, F.v2, O0, 0, 0, 0);
    O1 = __builtin_amdgcn_mfma_f32_16x16x32_bf16(pf1, F.v3, O1, 0, 0, 0);
    __builtin_amdgcn_s_setprio(0);
  };

  AFrags fA, fB;
  loadf(fA, 0);
  int kc = 0;
  while (true) {
    if (kc + 1 <= qc) loadf(fB, kc + 1);
    iterate(fA, kc, kc == qc);
    if (kc + 1 > qc) break;
    if (kc + 2 <= qc) loadf(fA, kc + 2);
    iterate(fB, kc + 1, kc + 1 == qc);
    if (kc + 2 > qc) break;
    kc += 2;
  }

#pragma unroll
  for (int r = 0; r < 4; ++r) {
    const int rr = lg * 4 + r;
    const int qrow = qbase + rr;
    float qmr = __shfl(qm, rr);
    float im = (float)imask[b * L_DIM + qrow];
    float scl = (1.f / lrow[r]) * qmr * im;
    if (qrow != 0) {
      float* op = &out[((size_t)(b * L_DIM + qrow)) * 256 + h * D_DIM];
      op[lc] = O0[r] * scl;
      op[16 + lc] = O1[r] * scl;
    }
  }
}

// ---------------------------------------------------------------------------
extern "C" void kernel_launch(void* const* d_in, const int* in_sizes, int n_in,
                              void* d_out, int out_size, void* d_ws, size_t ws_size,
                              hipStream_t stream) {
  (void)in_sizes; (void)n_in; (void)out_size; (void)ws_size;
  const float* query = (const float*)d_in[0];
  const float* input = (const float*)d_in[1];
  const int* imask = (const int*)d_in[2];
  const float* t_in = (const float*)d_in[3];
  const float* Wq = (const float*)d_in[5];
  const float* Wk = (const float*)d_in[6];
  const float* Wv = (const float*)d_in[7];
  const float* pW1 = (const float*)d_in[8],  *pb1 = (const float*)d_in[9];
  const float* pW2 = (const float*)d_in[10], *pb2 = (const float*)d_in[11];
  const float* sW1 = (const float*)d_in[12], *sb1 = (const float*)d_in[13];
  const float* sW2 = (const float*)d_in[14], *sb2 = (const float*)d_in[15];
  const float* bW1 = (const float*)d_in[16], *bb1 = (const float*)d_in[17];
  const float* bW2 = (const float*)d_in[18], *bb2 = (const float*)d_in[19];
  float* out = (float*)d_out;

  const int M = B_DIM * L_DIM;  // 4096
  char* p = (char*)d_ws;
  ushort_t* Qf = (ushort_t*)p;  p += (size_t)M * 256 * 2;   // 2 MB
  ushort_t* Kf = (ushort_t*)p;  p += (size_t)M * 256 * 2;
  ushort_t* Vf = (ushort_t*)p;  p += (size_t)M * 256 * 2;
  float* tkbuf = (float*)p;     // 4*1056*512*4 = 8.65 MB

  work_kernel<<<384 + B_DIM * NTILES_TOT, 256, 0, stream>>>(
      query, input, Wq, Wk, Wv, t_in,
      pW1, pb1, pW2, pb2, sW1, sb1, sW2, sb2, bW1, bb1, bW2, bb2,
      Qf, Kf, Vf, tkbuf);
  attn_row0_kernel<<<dim3(17, H_DIM, B_DIM), 256, 0, stream>>>(
      Qf, Kf, Vf, tkbuf, imask, out);
}

// Round 7
// 74.705 us; speedup vs baseline: 1.0241x; 1.0241x over previous
//
#include <hip/hip_runtime.h>
#include <math.h>

// Problem constants (fixed-shape harness: B=4, L=1024, U=256, H=8, dh=32, td=8)
#define B_DIM 4
#define L_DIM 1024
#define H_DIM 8
#define D_DIM 32
#define TD 8
#define NTILES_TOT 1056       // sum over 16-row q-tiles of k-tile count
#define SCALE 0.17677669529663687f          // 1/sqrt(32)

typedef unsigned short ushort_t;
typedef __attribute__((ext_vector_type(8))) short short8v;
typedef __attribute__((ext_vector_type(4))) float f32x4;

// causal tiling helpers (16-row q-tiles, 32-key k-tiles)
__device__ __forceinline__ int ntiles_of(int qt) { return (qt >> 1) + 1; }
__device__ __forceinline__ int off_of(int qt) {
  int m = qt >> 1;
  return (qt & 1) ? (m + 1) * (m + 1) : m * m + m;
}

__device__ __forceinline__ ushort_t f2bf(float f) {
  unsigned u = __builtin_bit_cast(unsigned, f);
  u += 0x7FFFu + ((u >> 16) & 1u);
  return (ushort_t)(u >> 16);
}
__device__ __forceinline__ float bf2f(ushort_t h) {
  return __builtin_bit_cast(float, ((unsigned)h) << 16);
}
__device__ __forceinline__ short8v pack84(float4 a, float4 b) {
  short8v r;
  r[0] = (short)f2bf(a.x); r[1] = (short)f2bf(a.y);
  r[2] = (short)f2bf(a.z); r[3] = (short)f2bf(a.w);
  r[4] = (short)f2bf(b.x); r[5] = (short)f2bf(b.y);
  r[6] = (short)f2bf(b.z); r[7] = (short)f2bf(b.w);
  return r;
}

// ---------------------------------------------------------------------------
// Kernel A: GEMM (blk < 384) + time-feature prep (blk >= 384). Independent
// parts share one dispatch so GEMM hides under prep's fp64 latency.
// GEMM: zero LDS / zero barriers. A-frags packed inline from X; B-frags read
// directly from global W (L2-resident, 16 scalar loads/kt). Writes bf16 frag
// buffers only: Qf (prescaled by SCALE) / Kf A-frag, Vf B-frag.
// prep: one thread per (pos, mlp z, out e); fp64; ptf = frac(period*t).
// ---------------------------------------------------------------------------
__global__ __launch_bounds__(256) void prep_gemm_kernel(
    const float* __restrict__ Xq, const float* __restrict__ Xi,
    const float* __restrict__ Wq, const float* __restrict__ Wk,
    const float* __restrict__ Wv, const float* __restrict__ t_in,
    const float* __restrict__ pW1, const float* __restrict__ pb1,
    const float* __restrict__ pW2, const float* __restrict__ pb2,
    const float* __restrict__ sW1, const float* __restrict__ sb1,
    const float* __restrict__ sW2, const float* __restrict__ sb2,
    const float* __restrict__ bW1, const float* __restrict__ bb1,
    const float* __restrict__ bW2, const float* __restrict__ bb2,
    ushort_t* __restrict__ Qf, ushort_t* __restrict__ Kf,
    ushort_t* __restrict__ Vf,
    float* __restrict__ ptf, float* __restrict__ sg, float* __restrict__ bs) {
  const int blk = blockIdx.x;
  const int tid = threadIdx.x;

  if (blk < 384) {
    // ------------------------- GEMM branch -------------------------
    const int z = blk >> 7;                 // 0..2 (Q,K,V)
    const int rem = blk & 127;
    const int m0 = (rem & 31) * 128;        // 128 rows
    const int n0 = (rem >> 5) * 64;         // 64 cols
    const float* X = (z == 0) ? Xq : Xi;
    const float* W = (z == 0) ? Wq : (z == 1) ? Wk : Wv;
    const int w = tid >> 6, l = tid & 63, lg = l >> 4, lc = l & 15;
    const int wm = w >> 1, wn = w & 1;

    f32x4 acc[4][2];
#pragma unroll
    for (int mi = 0; mi < 4; ++mi)
#pragma unroll
      for (int ni = 0; ni < 2; ++ni) acc[mi][ni] = (f32x4){0.f, 0.f, 0.f, 0.f};

    for (int kt0 = 0; kt0 < 8; ++kt0) {
      short8v a[4], bfr[2];
#pragma unroll
      for (int mi = 0; mi < 4; ++mi) {
        const float* xp = &X[(size_t)(m0 + (wm * 4 + mi) * 16 + lc) * 256 + kt0 * 32 + lg * 8];
        a[mi] = pack84(*(const float4*)xp, *(const float4*)(xp + 4));
      }
#pragma unroll
      for (int ni = 0; ni < 2; ++ni) {
        const int ncol = n0 + (wn * 2 + ni) * 16 + lc;
        short8v bf;
#pragma unroll
        for (int j = 0; j < 8; ++j)
          bf[j] = (short)f2bf(W[(size_t)(kt0 * 32 + lg * 8 + j) * 256 + ncol]);
        bfr[ni] = bf;
      }
#pragma unroll
      for (int mi = 0; mi < 4; ++mi)
#pragma unroll
        for (int ni = 0; ni < 2; ++ni)
          acc[mi][ni] = __builtin_amdgcn_mfma_f32_16x16x32_bf16(a[mi], bfr[ni], acc[mi][ni], 0, 0, 0);
    }

#pragma unroll
    for (int mi = 0; mi < 4; ++mi) {
#pragma unroll
      for (int ni = 0; ni < 2; ++ni) {
        const int col = n0 + wn * 32 + ni * 16 + lc;
        const int hh = col >> 5, d = col & 31;
#pragma unroll
        for (int r = 0; r < 4; ++r) {
          const int row = m0 + (wm * 4 + mi) * 16 + lg * 4 + r;
          const int bb = row >> 10, lr = row & (L_DIM - 1);
          float v = acc[mi][ni][r];
          if (z == 0) v *= SCALE;           // fold attention scale into Q
          const ushort_t bv = f2bf(v);
          if (z == 2) {
            Vf[(((size_t)(bb * H_DIM + hh) * 32 + (lr >> 5)) * 2 + (d >> 4)) * 512 +
               (((lr >> 3) & 3) * 16 + (d & 15)) * 8 + (lr & 7)] = bv;
          } else {
            ushort_t* of16 = (z == 0) ? Qf : Kf;
            of16[((size_t)((bb * H_DIM + hh) * 64 + (lr >> 4))) * 512 +
                 ((d >> 3) * 16 + (lr & 15)) * 8 + (d & 7)] = bv;
          }
        }
      }
    }
  } else {
    // ------------------------- prep branch -------------------------
    const int lin = (blk - 384) * 256 + tid;  // 131072 slots = 4096 pos * 32
    const int i = lin >> 5;
    const int slot = lin & 31;
    const int z = slot >> 3, e = slot & 7;    // z==3 slots idle
    if (z == 3) return;
    const float* W1 = (z == 0) ? pW1 : (z == 1) ? sW1 : bW1;
    const float* b1 = (z == 0) ? pb1 : (z == 1) ? sb1 : bb1;
    const float* W2 = (z == 0) ? pW2 : (z == 1) ? sW2 : bW2;
    const float* b2 = (z == 0) ? pb2 : (z == 1) ? sb2 : bb2;
    const double t = (double)t_in[i];
    double acc = (double)b2[e];
#pragma unroll
    for (int d = 0; d < 8; ++d) {
      double hv = t * (double)W1[d] + (double)b1[d];
      hv = hv > 0.0 ? hv : 0.0;
      acc += hv * (double)W2[d * 8 + e];
    }
    acc = acc > 0.0 ? acc : 0.0;
    const size_t o = (size_t)i * TD + e;
    if (z == 0) {
      double pt = acc * t;                    // period*t; fp64 frac once
      ptf[o] = (float)(pt - floor(pt));
    } else if (z == 1) {
      sg[o] = (float)(acc + 1e-6);
    } else {
      bs[o] = (float)acc;
    }
  }
}

// ---------------------------------------------------------------------------
// Kernel B: tk tiles (4224 uniform blocks, exact live-tile decode).
// q-side features hoisted to registers (per-thread i is constant); k-side
// read as b128 from stride-12 rows (2-way bank alias = free). Output in MFMA
// C-frag order, prescaled by SCALE. cos via v_cos (input in revolutions).
// ---------------------------------------------------------------------------
__global__ __launch_bounds__(256) void tk_kernel(
    const float* __restrict__ ptf, const float* __restrict__ sg,
    const float* __restrict__ bs, const float* __restrict__ t_in,
    float* __restrict__ tkbuf) {
  __shared__ __align__(16) float ptq[16 * 8], qsh[16 * 8], qbh[16 * 8];
  __shared__ __align__(16) float ptk[32 * 12], ksh[32 * 12], kbh[32 * 12];
  __shared__ float trow[16], tcol[32];
  const int blk = blockIdx.x;
  const int tid = threadIdx.x;

  const int b = blk / NTILES_TOT;
  const int t1 = blk - b * NTILES_TOT;      // 0..1055
  int m = (int)sqrtf((float)t1 + 1.0f);
  while (m * m + m > t1) --m;
  while ((m + 1) * (m + 1) + (m + 1) <= t1) ++m;
  const int rem = t1 - (m * m + m);
  int qt, kt;
  if (rem <= m) { qt = 2 * m; kt = rem; }
  else          { qt = 2 * m + 1; kt = rem - (m + 1); }
  const int q0 = qt << 4, k0 = kt << 5;

  if (tid < 16) trow[tid] = t_in[b * L_DIM + q0 + tid];
  if (tid < 32) tcol[tid] = t_in[b * L_DIM + k0 + tid];
  if (tid < 128) {
    const int i = tid >> 3, d = tid & 7;
    const size_t base = (size_t)(b * L_DIM + q0 + i) * TD + d;
    ptq[i * 8 + d] = ptf[base];
    qsh[i * 8 + d] = sg[base];
    qbh[i * 8 + d] = bs[base];
  }
  {
    const int j = tid >> 3, d = tid & 7;    // 32*8 = 256 exactly
    const size_t base = (size_t)(b * L_DIM + k0 + j) * TD + d;
    ptk[j * 12 + d] = ptf[base];
    ksh[j * 12 + d] = sg[base];
    kbh[j * 12 + d] = bs[base];
  }
  __syncthreads();

  const int r = tid & 3;
  const int lr2 = tid >> 2;                 // 0..63
  const int i = ((lr2 >> 4) << 2) | r;
  // hoist q-side into registers
  float pq[8], qs_[8], qb_[8];
  *(float4*)&pq[0]  = *(const float4*)&ptq[i * 8];
  *(float4*)&pq[4]  = *(const float4*)&ptq[i * 8 + 4];
  *(float4*)&qs_[0] = *(const float4*)&qsh[i * 8];
  *(float4*)&qs_[4] = *(const float4*)&qsh[i * 8 + 4];
  *(float4*)&qb_[0] = *(const float4*)&qbh[i * 8];
  *(float4*)&qb_[4] = *(const float4*)&qbh[i * 8 + 4];
  const float ti = trow[i];

  float* dst = &tkbuf[(size_t)(b * NTILES_TOT + off_of(qt) + kt) * 512];
#pragma unroll
  for (int pp = 0; pp < 2; ++pp) {
    const int j = pp * 16 + (lr2 & 15);
    float td2 = ti - tcol[j];
    td2 *= td2;
    float pk[8], ks_[8], kb_[8];
    *(float4*)&pk[0]  = *(const float4*)&ptk[j * 12];
    *(float4*)&pk[4]  = *(const float4*)&ptk[j * 12 + 4];
    *(float4*)&ks_[0] = *(const float4*)&ksh[j * 12];
    *(float4*)&ks_[4] = *(const float4*)&ksh[j * 12 + 4];
    *(float4*)&kb_[0] = *(const float4*)&kbh[j * 12];
    *(float4*)&kb_[4] = *(const float4*)&kbh[j * 12 + 4];
    float a = 0.f;
#pragma unroll
    for (int d = 0; d < TD; ++d) {
      const float sqd = qs_[d], skd = ks_[d];
      const float denom = sqd * sqd + skd * skd;
      const float inv = __builtin_amdgcn_rcpf(denom);
      const float ee = __expf(-td2 * inv);
      const float le = __builtin_amdgcn_sqrtf(2.f * sqd * skd * inv);
      const float dq = __builtin_fabsf(pq[d] - pk[d]);
      const float ce = __builtin_amdgcn_cosf(dq);  // revolutions
      a += qb_[d] * kb_[d] * (le * ee * ce);
    }
    dst[tid + (pp << 8)] = a * SCALE;       // fold attention scale into tk
  }
}

// ---------------------------------------------------------------------------
// Kernel C: ATTENTION (x<16, qc = 15-x LPT order) + ROW-0 fixup (x==16).
// 4 waves x 16 q-rows; frags straight from global bf16 buffers; LDS only for
// the wave-private P transpose. launch_bounds(256,4) caps VGPR at 128 ->
// 16 waves/CU so TLP hides L2 latency. Per-lane partial lsum (cross-lane
// reduce deferred to epilogue). Scores = QK' + tk' (both pre-scaled).
// ---------------------------------------------------------------------------
__global__ __launch_bounds__(256, 4) void attn_row0_kernel(
    const ushort_t* __restrict__ Qf, const ushort_t* __restrict__ Kf,
    const ushort_t* __restrict__ Vf, const float* __restrict__ tkbuf,
    const int* __restrict__ imask, float* __restrict__ out) {
  __shared__ __align__(16) ushort_t lds_p[4][1024];  // per-wave P (8 KB)
  __shared__ float p_s[L_DIM];                       // row0 (4 KB)
  __shared__ float qsh[D_DIM];
  __shared__ float red[8][33];
  __shared__ float rtmp[4];

  const int h = blockIdx.y;
  const int b = blockIdx.z;
  const int tid = threadIdx.x;
  const int fb = (b * H_DIM + h) * 64;   // frag-tile base (16-row tiles)
  const int vb = (b * H_DIM + h) * 32;   // V-group base (32-key groups)

  if (blockIdx.x == 16) {
    // ---------------- row-0 path ----------------
    if (tid < D_DIM)
      qsh[tid] = bf2f(Qf[(size_t)fb * 512 + (tid >> 3) * 128 + (tid & 7)]);
    __syncthreads();

    float lmax = -1e30f;
    for (int j = tid; j < L_DIM; j += 256) {
      int i = j & 15;
      float tkv = tkbuf[(size_t)(b * NTILES_TOT + off_of(j >> 4)) * 512 +
                        (((i >> 2) << 6) | (i & 3))];
      const ushort_t* kp = &Kf[(size_t)(fb + (j >> 4)) * 512 + (j & 15) * 8];
      float dot = 0.f;
#pragma unroll
      for (int o = 0; o < 4; ++o) {
        short8v kv = *(const short8v*)&kp[o * 128];
#pragma unroll
        for (int u = 0; u < 8; ++u) dot += qsh[o * 8 + u] * bf2f((ushort_t)kv[u]);
      }
      float sc = dot + tkv;               // both pre-scaled
      p_s[j] = sc;
      lmax = fmaxf(lmax, sc);
    }
#pragma unroll
    for (int o = 1; o < 64; o <<= 1) lmax = fmaxf(lmax, __shfl_xor(lmax, o));
    if ((tid & 63) == 0) rtmp[tid >> 6] = lmax;
    __syncthreads();
    const float bmax = fmaxf(fmaxf(rtmp[0], rtmp[1]), fmaxf(rtmp[2], rtmp[3]));
    __syncthreads();

    float lsumv = 0.f;
    for (int j = tid; j < L_DIM; j += 256) {
      float pv = __expf(p_s[j] - bmax);
      p_s[j] = pv;
      lsumv += pv;
    }
#pragma unroll
    for (int o = 1; o < 64; o <<= 1) lsumv += __shfl_xor(lsumv, o);
    if ((tid & 63) == 0) rtmp[tid >> 6] = lsumv;
    __syncthreads();
    const float bsum = rtmp[0] + rtmp[1] + rtmp[2] + rtmp[3];

    const int g = tid >> 5, d = tid & 31;
    float a = 0.f;
    for (int j = g * 128; j < g * 128 + 128; ++j) {
      float v = bf2f(Vf[(((size_t)(vb + (j >> 5))) * 2 + (d >> 4)) * 512 +
                        (((j >> 3) & 3) * 16 + (d & 15)) * 8 + (j & 7)]);
      a = fmaf(p_s[j], v, a);
    }
    red[g][d] = a;
    __syncthreads();
    if (tid < D_DIM) {
      float acc = 0.f;
#pragma unroll
      for (int gg = 0; gg < 8; ++gg) acc += red[gg][tid];
      float qabs = 0.f;
#pragma unroll
      for (int dd = 0; dd < D_DIM; ++dd) qabs += fabsf(qsh[dd]);
      const float qmv = qabs > 0.f ? 1.f : 0.f;
      out[((size_t)b * L_DIM) * 256 + h * D_DIM + tid] =
          acc * (1.0f / bsum) * qmv * (float)imask[b * L_DIM];
    }
    return;
  }

  // ---------------- attention path ----------------
  const int qc = 15 - (int)blockIdx.x;    // LPT: longest chunks first
  const int w = tid >> 6;
  const int l = tid & 63;
  const int lg = l >> 4;
  const int lc = l & 15;
  const int qbase = qc * 64 + w * 16;
  const int qt = qbase >> 4;

  short8v qfrag = *(const short8v*)&Qf[((size_t)(fb + qt)) * 512 + l * 8];
  float qabs_l = 0.f;
#pragma unroll
  for (int j = 0; j < 8; ++j) qabs_l += fabsf(bf2f((ushort_t)qfrag[j]));
  qabs_l += __shfl_xor(qabs_l, 16);
  qabs_l += __shfl_xor(qabs_l, 32);
  const float qm = (qabs_l > 0.f) ? 1.f : 0.f;

  f32x4 O0 = {0.f, 0.f, 0.f, 0.f};
  f32x4 O1 = {0.f, 0.f, 0.f, 0.f};
  float mrow[4] = {-1e30f, -1e30f, -1e30f, -1e30f};
  float lrow[4] = {0.f, 0.f, 0.f, 0.f};   // per-lane partial sums
  const float* tk_qt = &tkbuf[(size_t)(b * NTILES_TOT + off_of(qt)) * 512];
  ushort_t* Pw = lds_p[w];

  for (int kc = 0; kc <= qc; ++kc) {
    const bool diag = (kc == qc);
    // loads for this chunk (issued together; TLP hides latency)
    const size_t kb_ = ((size_t)(fb + kc * 4)) * 512 + l * 8;
    short8v kf0 = *(const short8v*)&Kf[kb_];
    short8v kf1 = *(const short8v*)&Kf[kb_ + 512];
    short8v kf2 = *(const short8v*)&Kf[kb_ + 1024];
    short8v kf3 = *(const short8v*)&Kf[kb_ + 1536];
    const size_t tb_ = (size_t)(kc * 2) * 512 + l * 4;
    float4 t0 = *(const float4*)&tk_qt[tb_];
    float4 t1 = *(const float4*)&tk_qt[tb_ + 256];
    float4 t2 = *(const float4*)&tk_qt[tb_ + 512];
    float4 t3 = *(const float4*)&tk_qt[tb_ + 768];
    const size_t vb_ = ((size_t)(vb + kc * 2)) * 1024 + l * 8;
    short8v vf0 = *(const short8v*)&Vf[vb_];
    short8v vf1 = *(const short8v*)&Vf[vb_ + 512];
    short8v vf2 = *(const short8v*)&Vf[vb_ + 1024];
    short8v vf3 = *(const short8v*)&Vf[vb_ + 1536];

    f32x4 z4 = {0.f, 0.f, 0.f, 0.f};
    __builtin_amdgcn_s_setprio(1);
    f32x4 sv0 = __builtin_amdgcn_mfma_f32_16x16x32_bf16(qfrag, kf0, z4, 0, 0, 0);
    f32x4 sv1 = __builtin_amdgcn_mfma_f32_16x16x32_bf16(qfrag, kf1, z4, 0, 0, 0);
    f32x4 sv2 = __builtin_amdgcn_mfma_f32_16x16x32_bf16(qfrag, kf2, z4, 0, 0, 0);
    f32x4 sv3 = __builtin_amdgcn_mfma_f32_16x16x32_bf16(qfrag, kf3, z4, 0, 0, 0);
    __builtin_amdgcn_s_setprio(0);

    float s[4][4];
#pragma unroll
    for (int r = 0; r < 4; ++r) {
      s[0][r] = sv0[r] + (&t0.x)[r];
      s[1][r] = sv1[r] + (&t1.x)[r];
      s[2][r] = sv2[r] + (&t2.x)[r];
      s[3][r] = sv3[r] + (&t3.x)[r];
    }
    if (diag) {
#pragma unroll
      for (int kt = 0; kt < 4; ++kt) {
        const int col = kc * 64 + kt * 16 + lc;
#pragma unroll
        for (int r = 0; r < 4; ++r)
          if (col >= qbase + lg * 4 + r) s[kt][r] = -10000.0f;
      }
    }

#pragma unroll
    for (int r = 0; r < 4; ++r) {
      float tmax = fmaxf(fmaxf(s[0][r], s[1][r]), fmaxf(s[2][r], s[3][r]));
      tmax = fmaxf(tmax, __shfl_xor(tmax, 1));
      tmax = fmaxf(tmax, __shfl_xor(tmax, 2));
      tmax = fmaxf(tmax, __shfl_xor(tmax, 4));
      tmax = fmaxf(tmax, __shfl_xor(tmax, 8));
      float mnew = fmaxf(mrow[r], tmax);
      float cf = __expf(mrow[r] - mnew);
      mrow[r] = mnew;
      float p0 = __expf(s[0][r] - mnew);
      float p1 = __expf(s[1][r] - mnew);
      float p2 = __expf(s[2][r] - mnew);
      float p3 = __expf(s[3][r] - mnew);
      lrow[r] = lrow[r] * cf + ((p0 + p1) + (p2 + p3));  // per-lane partial
      O0[r] *= cf;
      O1[r] *= cf;
      const int pb = ((lc >> 3) << 7) + ((lg * 4 + r) << 3) + (lc & 7);
      Pw[pb] = f2bf(p0);
      Pw[pb + 256] = f2bf(p1);
      Pw[pb + 512] = f2bf(p2);
      Pw[pb + 768] = f2bf(p3);
    }
    short8v pf0 = *(const short8v*)&Pw[l * 8];
    short8v pf1 = *(const short8v*)&Pw[(64 + l) * 8];
    __builtin_amdgcn_s_setprio(1);
    O0 = __builtin_amdgcn_mfma_f32_16x16x32_bf16(pf0, vf0, O0, 0, 0, 0);
    O1 = __builtin_amdgcn_mfma_f32_16x16x32_bf16(pf0, vf1, O1, 0, 0, 0);
    O0 = __builtin_amdgcn_mfma_f32_16x16x32_bf16(pf1, vf2, O0, 0, 0, 0);
    O1 = __builtin_amdgcn_mfma_f32_16x16x32_bf16(pf1, vf3, O1, 0, 0, 0);
    __builtin_amdgcn_s_setprio(0);
  }

  // epilogue: finish lsum cross-lane reduce, mask, store
#pragma unroll
  for (int r = 0; r < 4; ++r) {
    lrow[r] += __shfl_xor(lrow[r], 1);
    lrow[r] += __shfl_xor(lrow[r], 2);
    lrow[r] += __shfl_xor(lrow[r], 4);
    lrow[r] += __shfl_xor(lrow[r], 8);
    const int rr = lg * 4 + r;
    const int qrow = qbase + rr;
    float qmr = __shfl(qm, rr);
    float im = (float)imask[b * L_DIM + qrow];
    float scl = (1.f / lrow[r]) * qmr * im;
    if (qrow != 0) {
      float* op = &out[((size_t)(b * L_DIM + qrow)) * 256 + h * D_DIM];
      op[lc] = O0[r] * scl;
      op[16 + lc] = O1[r] * scl;
    }
  }
}

// ---------------------------------------------------------------------------
extern "C" void kernel_launch(void* const* d_in, const int* in_sizes, int n_in,
                              void* d_out, int out_size, void* d_ws, size_t ws_size,
                              hipStream_t stream) {
  (void)in_sizes; (void)n_in; (void)out_size; (void)ws_size;
  const float* query = (const float*)d_in[0];
  const float* input = (const float*)d_in[1];
  const int* imask = (const int*)d_in[2];
  const float* t_in = (const float*)d_in[3];
  const float* Wq = (const float*)d_in[5];
  const float* Wk = (const float*)d_in[6];
  const float* Wv = (const float*)d_in[7];
  const float* pW1 = (const float*)d_in[8],  *pb1 = (const float*)d_in[9];
  const float* pW2 = (const float*)d_in[10], *pb2 = (const float*)d_in[11];
  const float* sW1 = (const float*)d_in[12], *sb1 = (const float*)d_in[13];
  const float* sW2 = (const float*)d_in[14], *sb2 = (const float*)d_in[15];
  const float* bW1 = (const float*)d_in[16], *bb1 = (const float*)d_in[17];
  const float* bW2 = (const float*)d_in[18], *bb2 = (const float*)d_in[19];
  float* out = (float*)d_out;

  const int M = B_DIM * L_DIM;  // 4096
  char* p = (char*)d_ws;
  ushort_t* Qf = (ushort_t*)p;  p += (size_t)M * 256 * 2;   // 2 MB
  ushort_t* Kf = (ushort_t*)p;  p += (size_t)M * 256 * 2;
  ushort_t* Vf = (ushort_t*)p;  p += (size_t)M * 256 * 2;
  float* ptf = (float*)p;       p += (size_t)M * TD * 4;
  float* sg = (float*)p;        p += (size_t)M * TD * 4;
  float* bs = (float*)p;        p += (size_t)M * TD * 4;
  float* tkbuf = (float*)p;     // 4*1056*512*4 = 8.65 MB

  prep_gemm_kernel<<<384 + 512, 256, 0, stream>>>(
      query, input, Wq, Wk, Wv, t_in,
      pW1, pb1, pW2, pb2, sW1, sb1, sW2, sb2, bW1, bb1, bW2, bb2,
      Qf, Kf, Vf, ptf, sg, bs);
  tk_kernel<<<B_DIM * NTILES_TOT, 256, 0, stream>>>(ptf, sg, bs, t_in, tkbuf);
  attn_row0_kernel<<<dim3(17, H_DIM, B_DIM), 256, 0, stream>>>(
      Qf, Kf, Vf, tkbuf, imask, out);
}

// Round 8
// 60.688 us; speedup vs baseline: 1.2606x; 1.2310x over previous
//
#include <hip/hip_runtime.h>
#include <math.h>

// Problem constants (fixed-shape harness: B=4, L=1024, U=256, H=8, dh=32, td=8)
#define B_DIM 4
#define L_DIM 1024
#define H_DIM 8
#define D_DIM 32
#define TD 8
#define NTILES_TOT 1056       // sum over 16-row q-tiles of 32-key k-tile count
#define SCALE 0.17677669529663687f          // 1/sqrt(32)

typedef unsigned short ushort_t;
typedef __attribute__((ext_vector_type(8))) short short8v;
typedef __attribute__((ext_vector_type(4))) float f32x4;

// causal tiling helpers (16-row q-tiles, 32-key k-tiles)
__device__ __forceinline__ int ntiles_of(int qt) { return (qt >> 1) + 1; }
__device__ __forceinline__ int off_of(int qt) {
  int m = qt >> 1;
  return (qt & 1) ? (m + 1) * (m + 1) : m * m + m;
}
// (qc, seg) from flattened partial index x in 0..39; segs of <=4 kc-chunks
__device__ __forceinline__ void qcseg(int x, int& qc, int& s) {
  if (x < 4) { qc = x; s = 0; }
  else if (x < 12) { qc = 4 + ((x - 4) >> 1); s = (x - 4) & 1; }
  else if (x < 24) { int t = x - 12; qc = 8 + t / 3; s = t % 3; }
  else { int t = x - 24; qc = 12 + (t >> 2); s = t & 3; }
}

__device__ __forceinline__ ushort_t f2bf(float f) {
  unsigned u = __builtin_bit_cast(unsigned, f);
  u += 0x7FFFu + ((u >> 16) & 1u);
  return (ushort_t)(u >> 16);
}
__device__ __forceinline__ float bf2f(ushort_t h) {
  return __builtin_bit_cast(float, ((unsigned)h) << 16);
}
__device__ __forceinline__ short8v pack84(float4 a, float4 b) {
  short8v r;
  r[0] = (short)f2bf(a.x); r[1] = (short)f2bf(a.y);
  r[2] = (short)f2bf(a.z); r[3] = (short)f2bf(a.w);
  r[4] = (short)f2bf(b.x); r[5] = (short)f2bf(b.y);
  r[6] = (short)f2bf(b.z); r[7] = (short)f2bf(b.w);
  return r;
}

// ---------------------------------------------------------------------------
// Kernel 1: PREP = time-features + X bf16-frag pack + W bf16-frag pack.
// ---------------------------------------------------------------------------
__global__ __launch_bounds__(256) void prep_kernel(
    const float* __restrict__ t_in,
    const float* __restrict__ pW1, const float* __restrict__ pb1,
    const float* __restrict__ pW2, const float* __restrict__ pb2,
    const float* __restrict__ sW1, const float* __restrict__ sb1,
    const float* __restrict__ sW2, const float* __restrict__ sb2,
    const float* __restrict__ bW1, const float* __restrict__ bb1,
    const float* __restrict__ bW2, const float* __restrict__ bb2,
    float* __restrict__ ptf, float* __restrict__ sg, float* __restrict__ bs,
    const float* __restrict__ Xq, const float* __restrict__ Xi,
    ushort_t* __restrict__ Xfq, ushort_t* __restrict__ Xfi,
    const float* __restrict__ Wq, const float* __restrict__ Wk,
    const float* __restrict__ Wv, ushort_t* __restrict__ Wf) {
  const int blk = blockIdx.x;
  const int tid = threadIdx.x;
  if (blk < 512) {
    const int lin = blk * 256 + tid;        // 131072 slots = 4096 pos * 32
    const int i = lin >> 5;
    const int slot = lin & 31;
    const int z = slot >> 3, e = slot & 7;  // z==3 slots idle
    if (z == 3) return;
    const float* W1 = (z == 0) ? pW1 : (z == 1) ? sW1 : bW1;
    const float* b1 = (z == 0) ? pb1 : (z == 1) ? sb1 : bb1;
    const float* W2 = (z == 0) ? pW2 : (z == 1) ? sW2 : bW2;
    const float* b2 = (z == 0) ? pb2 : (z == 1) ? sb2 : bb2;
    const double t = (double)t_in[i];
    double acc = (double)b2[e];
#pragma unroll
    for (int d = 0; d < 8; ++d) {
      double hv = t * (double)W1[d] + (double)b1[d];
      hv = hv > 0.0 ? hv : 0.0;
      acc += hv * (double)W2[d * 8 + e];
    }
    acc = acc > 0.0 ? acc : 0.0;
    const size_t o = (size_t)i * TD + e;
    if (z == 0) {
      double pt = acc * t;                  // period*t; fp64 frac once
      ptf[o] = (float)(pt - floor(pt));
    } else if (z == 1) {
      sg[o] = (float)(acc + 1e-6);
    } else {
      bs[o] = (float)acc;
    }
  } else if (blk < 1536) {
    const int xb = blk - 512;               // 0..1023
    const float* X = (xb < 512) ? Xq : Xi;
    ushort_t* O = (xb < 512) ? Xfq : Xfi;
    const int lin = (xb & 511) * 256 + tid; // 131072 = 4096 rows * 32 octets
    const int row = lin >> 5, q = lin & 31;
    const float* src = &X[(size_t)row * 256 + q * 8];
    short8v f = pack84(*(const float4*)src, *(const float4*)(src + 4));
    size_t idx = ((size_t)((row >> 4) * 8 + (q >> 2)) * 64 + (q & 3) * 16 + (row & 15)) * 8;
    *(short8v*)&O[idx] = f;
  } else {
    const int wb = blk - 1536;              // 0..95
    const int z = wb >> 5;
    const float* W = (z == 0) ? Wq : (z == 1) ? Wk : Wv;
    const int lin = (wb & 31) * 256 + tid;  // 0..8191
    const int kt = lin >> 10, g = (lin >> 8) & 3, n = lin & 255;
    short8v f;
#pragma unroll
    for (int i2 = 0; i2 < 8; ++i2)
      f[i2] = (short)f2bf(W[(size_t)(kt * 32 + g * 8 + i2) * 256 + n]);
    size_t idx = ((size_t)((z * 8 + kt) * 16 + (n >> 4)) * 64 + g * 16 + (n & 15)) * 8;
    *(short8v*)&Wf[idx] = f;
  }
}

// ---------------------------------------------------------------------------
// Kernel 2: WORK = QKV MFMA GEMM from packed frags (blk<384, zero LDS/zero
// barriers, coalesced b128 loads) + tk tiles (blk>=384, reg-hoisted q-side).
// Qf prescaled by SCALE; tkbuf prescaled by SCALE.
// ---------------------------------------------------------------------------
__global__ __launch_bounds__(256) void work_kernel(
    const ushort_t* __restrict__ Xfq, const ushort_t* __restrict__ Xfi,
    const ushort_t* __restrict__ Wf,
    ushort_t* __restrict__ Qf, ushort_t* __restrict__ Kf,
    ushort_t* __restrict__ Vf,
    const float* __restrict__ ptf, const float* __restrict__ sg,
    const float* __restrict__ bs, const float* __restrict__ t_in,
    float* __restrict__ tkbuf) {
  __shared__ __align__(16) float ptq[16 * 8], qsh[16 * 8], qbh[16 * 8];
  __shared__ __align__(16) float ptk[32 * 12], ksh[32 * 12], kbh[32 * 12];
  __shared__ float trow[16], tcol[32];
  const int blk = blockIdx.x;
  const int tid = threadIdx.x;

  if (blk < 384) {
    const int z = blk >> 7;                 // 0..2 (Q,K,V)
    const int rem = blk & 127;
    const int m0t = (rem & 31) * 8;         // 8 row-tiles of 16 = 128 rows
    const int n0 = (rem >> 5) * 64;
    const ushort_t* Xf = (z == 0) ? Xfq : Xfi;
    const int w = tid >> 6, l = tid & 63, lg = l >> 4, lc = l & 15;
    const int wm = w >> 1, wn = w & 1;

    f32x4 acc[4][2];
#pragma unroll
    for (int mi = 0; mi < 4; ++mi)
#pragma unroll
      for (int ni = 0; ni < 2; ++ni) acc[mi][ni] = (f32x4){0.f, 0.f, 0.f, 0.f};

    for (int kt0 = 0; kt0 < 8; ++kt0) {
      short8v a[4], bfr[2];
#pragma unroll
      for (int mi = 0; mi < 4; ++mi)
        a[mi] = *(const short8v*)&Xf[((size_t)(m0t + wm * 4 + mi) * 8 + kt0) * 512 + l * 8];
#pragma unroll
      for (int ni = 0; ni < 2; ++ni)
        bfr[ni] = *(const short8v*)&Wf[((size_t)(z * 8 + kt0) * 16 + (n0 >> 4) + wn * 2 + ni) * 512 + l * 8];
#pragma unroll
      for (int mi = 0; mi < 4; ++mi)
#pragma unroll
        for (int ni = 0; ni < 2; ++ni)
          acc[mi][ni] = __builtin_amdgcn_mfma_f32_16x16x32_bf16(a[mi], bfr[ni], acc[mi][ni], 0, 0, 0);
    }

#pragma unroll
    for (int mi = 0; mi < 4; ++mi) {
#pragma unroll
      for (int ni = 0; ni < 2; ++ni) {
        const int col = n0 + wn * 32 + ni * 16 + lc;
        const int hh = col >> 5, d = col & 31;
#pragma unroll
        for (int r = 0; r < 4; ++r) {
          const int row = (m0t + wm * 4 + mi) * 16 + lg * 4 + r;
          const int bb = row >> 10, lr = row & (L_DIM - 1);
          float v = acc[mi][ni][r];
          if (z == 0) v *= SCALE;           // fold attention scale into Q
          const ushort_t bv = f2bf(v);
          if (z == 2) {
            Vf[(((size_t)(bb * H_DIM + hh) * 32 + (lr >> 5)) * 2 + (d >> 4)) * 512 +
               (((lr >> 3) & 3) * 16 + (d & 15)) * 8 + (lr & 7)] = bv;
          } else {
            ushort_t* of16 = (z == 0) ? Qf : Kf;
            of16[((size_t)((bb * H_DIM + hh) * 64 + (lr >> 4))) * 512 +
                 ((d >> 3) * 16 + (lr & 15)) * 8 + (d & 7)] = bv;
          }
        }
      }
    }
  } else {
    // ------------------------- tk branch -------------------------
    const int lin = blk - 384;              // 0..4223
    const int b = lin / NTILES_TOT;
    const int t1 = lin - b * NTILES_TOT;    // 0..1055
    int m = (int)sqrtf((float)t1 + 1.0f);
    while (m * m + m > t1) --m;
    while ((m + 1) * (m + 1) + (m + 1) <= t1) ++m;
    const int rem = t1 - (m * m + m);
    int qt, kt;
    if (rem <= m) { qt = 2 * m; kt = rem; }
    else          { qt = 2 * m + 1; kt = rem - (m + 1); }
    const int q0 = qt << 4, k0 = kt << 5;

    if (tid < 16) trow[tid] = t_in[b * L_DIM + q0 + tid];
    if (tid < 32) tcol[tid] = t_in[b * L_DIM + k0 + tid];
    if (tid < 128) {
      const int i = tid >> 3, d = tid & 7;
      const size_t base = (size_t)(b * L_DIM + q0 + i) * TD + d;
      ptq[i * 8 + d] = ptf[base];
      qsh[i * 8 + d] = sg[base];
      qbh[i * 8 + d] = bs[base];
    }
    {
      const int j = tid >> 3, d = tid & 7;  // 32*8 = 256 exactly
      const size_t base = (size_t)(b * L_DIM + k0 + j) * TD + d;
      ptk[j * 12 + d] = ptf[base];
      ksh[j * 12 + d] = sg[base];
      kbh[j * 12 + d] = bs[base];
    }
    __syncthreads();

    const int r = tid & 3;
    const int lr2 = tid >> 2;               // 0..63
    const int i = ((lr2 >> 4) << 2) | r;
    float pq[8], qs_[8], qb_[8];
    *(float4*)&pq[0]  = *(const float4*)&ptq[i * 8];
    *(float4*)&pq[4]  = *(const float4*)&ptq[i * 8 + 4];
    *(float4*)&qs_[0] = *(const float4*)&qsh[i * 8];
    *(float4*)&qs_[4] = *(const float4*)&qsh[i * 8 + 4];
    *(float4*)&qb_[0] = *(const float4*)&qbh[i * 8];
    *(float4*)&qb_[4] = *(const float4*)&qbh[i * 8 + 4];
    const float ti = trow[i];

    float* dst = &tkbuf[(size_t)(b * NTILES_TOT + off_of(qt) + kt) * 512];
#pragma unroll
    for (int pp = 0; pp < 2; ++pp) {
      const int j = pp * 16 + (lr2 & 15);
      float td2 = ti - tcol[j];
      td2 *= td2;
      float pk[8], ks_[8], kb_[8];
      *(float4*)&pk[0]  = *(const float4*)&ptk[j * 12];
      *(float4*)&pk[4]  = *(const float4*)&ptk[j * 12 + 4];
      *(float4*)&ks_[0] = *(const float4*)&ksh[j * 12];
      *(float4*)&ks_[4] = *(const float4*)&ksh[j * 12 + 4];
      *(float4*)&kb_[0] = *(const float4*)&kbh[j * 12];
      *(float4*)&kb_[4] = *(const float4*)&kbh[j * 12 + 4];
      float a = 0.f;
#pragma unroll
      for (int d = 0; d < TD; ++d) {
        const float sqd = qs_[d], skd = ks_[d];
        const float denom = sqd * sqd + skd * skd;
        const float inv = __builtin_amdgcn_rcpf(denom);
        const float ee = __expf(-td2 * inv);
        const float le = __builtin_amdgcn_sqrtf(2.f * sqd * skd * inv);
        const float dq = __builtin_fabsf(pq[d] - pk[d]);
        const float ce = __builtin_amdgcn_cosf(dq);  // revolutions
        a += qb_[d] * kb_[d] * (le * ee * ce);
      }
      dst[tid + (pp << 8)] = a * SCALE;     // fold attention scale into tk
    }
  }
}

// ---------------------------------------------------------------------------
// Kernel 3: ATTENTION PARTIAL. Grid (40, 8, 4): x -> (qc, seg), each block
// processes <=4 k-chunks of its 64-row q-chunk; writes unnormalized partial
// O and per-row (m, l) to workspace. 1280 near-uniform blocks -> ~5/CU.
// ---------------------------------------------------------------------------
__global__ __launch_bounds__(256, 4) void attn_partial_kernel(
    const ushort_t* __restrict__ Qf, const ushort_t* __restrict__ Kf,
    const ushort_t* __restrict__ Vf, const float* __restrict__ tkbuf,
    float* __restrict__ Opart, float* __restrict__ MLpart) {
  __shared__ __align__(16) ushort_t lds_p[4][1024];  // per-wave P (8 KB)
  const int h = blockIdx.y;
  const int b = blockIdx.z;
  int qc, seg;
  qcseg((int)blockIdx.x, qc, seg);
  const int tid = threadIdx.x;
  const int w = tid >> 6;
  const int l = tid & 63;
  const int lg = l >> 4;
  const int lc = l & 15;
  const int qbase = qc * 64 + w * 16;
  const int qt = qbase >> 4;
  const int fb = (b * H_DIM + h) * 64;
  const int vb = (b * H_DIM + h) * 32;

  short8v qfrag = *(const short8v*)&Qf[((size_t)(fb + qt)) * 512 + l * 8];

  f32x4 O0 = {0.f, 0.f, 0.f, 0.f};
  f32x4 O1 = {0.f, 0.f, 0.f, 0.f};
  float mrow[4] = {-1e30f, -1e30f, -1e30f, -1e30f};
  float lrow[4] = {0.f, 0.f, 0.f, 0.f};   // per-lane partials
  const float* tk_qt = &tkbuf[(size_t)(b * NTILES_TOT + off_of(qt)) * 512];
  ushort_t* Pw = lds_p[w];

  const int kc0 = seg * 4;
  const int kc1 = (kc0 + 3 < qc) ? kc0 + 3 : qc;
  for (int kc = kc0; kc <= kc1; ++kc) {
    const bool diag = (kc == qc);
    const size_t kb_ = ((size_t)(fb + kc * 4)) * 512 + l * 8;
    short8v kf0 = *(const short8v*)&Kf[kb_];
    short8v kf1 = *(const short8v*)&Kf[kb_ + 512];
    short8v kf2 = *(const short8v*)&Kf[kb_ + 1024];
    short8v kf3 = *(const short8v*)&Kf[kb_ + 1536];
    const size_t tb_ = (size_t)(kc * 2) * 512 + l * 4;
    float4 t0 = *(const float4*)&tk_qt[tb_];
    float4 t1 = *(const float4*)&tk_qt[tb_ + 256];
    float4 t2 = *(const float4*)&tk_qt[tb_ + 512];
    float4 t3 = *(const float4*)&tk_qt[tb_ + 768];
    const size_t vb_ = ((size_t)(vb + kc * 2)) * 1024 + l * 8;
    short8v vf0 = *(const short8v*)&Vf[vb_];
    short8v vf1 = *(const short8v*)&Vf[vb_ + 512];
    short8v vf2 = *(const short8v*)&Vf[vb_ + 1024];
    short8v vf3 = *(const short8v*)&Vf[vb_ + 1536];

    f32x4 z4 = {0.f, 0.f, 0.f, 0.f};
    __builtin_amdgcn_s_setprio(1);
    f32x4 sv0 = __builtin_amdgcn_mfma_f32_16x16x32_bf16(qfrag, kf0, z4, 0, 0, 0);
    f32x4 sv1 = __builtin_amdgcn_mfma_f32_16x16x32_bf16(qfrag, kf1, z4, 0, 0, 0);
    f32x4 sv2 = __builtin_amdgcn_mfma_f32_16x16x32_bf16(qfrag, kf2, z4, 0, 0, 0);
    f32x4 sv3 = __builtin_amdgcn_mfma_f32_16x16x32_bf16(qfrag, kf3, z4, 0, 0, 0);
    __builtin_amdgcn_s_setprio(0);

    float s[4][4];
#pragma unroll
    for (int r = 0; r < 4; ++r) {
      s[0][r] = sv0[r] + (&t0.x)[r];
      s[1][r] = sv1[r] + (&t1.x)[r];
      s[2][r] = sv2[r] + (&t2.x)[r];
      s[3][r] = sv3[r] + (&t3.x)[r];
    }
    if (diag) {
#pragma unroll
      for (int kt = 0; kt < 4; ++kt) {
        const int col = kc * 64 + kt * 16 + lc;
#pragma unroll
        for (int r = 0; r < 4; ++r)
          if (col >= qbase + lg * 4 + r) s[kt][r] = -10000.0f;
      }
    }

#pragma unroll
    for (int r = 0; r < 4; ++r) {
      float tmax = fmaxf(fmaxf(s[0][r], s[1][r]), fmaxf(s[2][r], s[3][r]));
      tmax = fmaxf(tmax, __shfl_xor(tmax, 1));
      tmax = fmaxf(tmax, __shfl_xor(tmax, 2));
      tmax = fmaxf(tmax, __shfl_xor(tmax, 4));
      tmax = fmaxf(tmax, __shfl_xor(tmax, 8));
      float mnew = fmaxf(mrow[r], tmax);
      float cf = __expf(mrow[r] - mnew);
      mrow[r] = mnew;
      float p0 = __expf(s[0][r] - mnew);
      float p1 = __expf(s[1][r] - mnew);
      float p2 = __expf(s[2][r] - mnew);
      float p3 = __expf(s[3][r] - mnew);
      lrow[r] = lrow[r] * cf + ((p0 + p1) + (p2 + p3));
      O0[r] *= cf;
      O1[r] *= cf;
      const int pb = ((lc >> 3) << 7) + ((lg * 4 + r) << 3) + (lc & 7);
      Pw[pb] = f2bf(p0);
      Pw[pb + 256] = f2bf(p1);
      Pw[pb + 512] = f2bf(p2);
      Pw[pb + 768] = f2bf(p3);
    }
    short8v pf0 = *(const short8v*)&Pw[l * 8];
    short8v pf1 = *(const short8v*)&Pw[(64 + l) * 8];
    __builtin_amdgcn_s_setprio(1);
    O0 = __builtin_amdgcn_mfma_f32_16x16x32_bf16(pf0, vf0, O0, 0, 0, 0);
    O1 = __builtin_amdgcn_mfma_f32_16x16x32_bf16(pf0, vf1, O1, 0, 0, 0);
    O0 = __builtin_amdgcn_mfma_f32_16x16x32_bf16(pf1, vf2, O0, 0, 0, 0);
    O1 = __builtin_amdgcn_mfma_f32_16x16x32_bf16(pf1, vf3, O1, 0, 0, 0);
    __builtin_amdgcn_s_setprio(0);
  }

  // store partials
  const int pslot = (b * H_DIM + h) * 16 + qc;
  float* Ob = &Opart[(size_t)pslot * 8192 + seg * 2048];
  *(f32x4*)&Ob[tid * 8] = O0;
  *(f32x4*)&Ob[tid * 8 + 4] = O1;
  float* mlb = &MLpart[(size_t)pslot * 512 + seg * 128];
#pragma unroll
  for (int r = 0; r < 4; ++r) {
    float lr_ = lrow[r];
    lr_ += __shfl_xor(lr_, 1);
    lr_ += __shfl_xor(lr_, 2);
    lr_ += __shfl_xor(lr_, 4);
    lr_ += __shfl_xor(lr_, 8);
    if (lc == 0) {
      mlb[w * 16 + lg * 4 + r] = mrow[r];
      mlb[64 + w * 16 + lg * 4 + r] = lr_;
    }
  }
}

// ---------------------------------------------------------------------------
// Kernel 4: COMBINE (x<16) + ROW-0 (x==16). Combine merges <=4 partials per
// row with flash rescale, applies masks, stores. Row0 = full-key softmax.
// ---------------------------------------------------------------------------
__global__ __launch_bounds__(256) void combine_row0_kernel(
    const ushort_t* __restrict__ Qf, const ushort_t* __restrict__ Kf,
    const ushort_t* __restrict__ Vf, const float* __restrict__ tkbuf,
    const float* __restrict__ Opart, const float* __restrict__ MLpart,
    const int* __restrict__ imask, float* __restrict__ out) {
  __shared__ float p_s[L_DIM];
  __shared__ float qsh[D_DIM];
  __shared__ float red[8][33];
  __shared__ float rtmp[4];
  const int h = blockIdx.y;
  const int b = blockIdx.z;
  const int tid = threadIdx.x;
  const int fb = (b * H_DIM + h) * 64;
  const int vb = (b * H_DIM + h) * 32;

  if (blockIdx.x == 16) {
    // ---------------- row-0 path ----------------
    if (tid < D_DIM)
      qsh[tid] = bf2f(Qf[(size_t)fb * 512 + (tid >> 3) * 128 + (tid & 7)]);
    __syncthreads();
    float lmax = -1e30f;
    for (int j = tid; j < L_DIM; j += 256) {
      int i = j & 15;
      float tkv = tkbuf[(size_t)(b * NTILES_TOT + off_of(j >> 4)) * 512 +
                        (((i >> 2) << 6) | (i & 3))];
      const ushort_t* kp = &Kf[(size_t)(fb + (j >> 4)) * 512 + (j & 15) * 8];
      float dot = 0.f;
#pragma unroll
      for (int o = 0; o < 4; ++o) {
        short8v kv = *(const short8v*)&kp[o * 128];
#pragma unroll
        for (int u = 0; u < 8; ++u) dot += qsh[o * 8 + u] * bf2f((ushort_t)kv[u]);
      }
      float sc = dot + tkv;               // both pre-scaled
      p_s[j] = sc;
      lmax = fmaxf(lmax, sc);
    }
#pragma unroll
    for (int o = 1; o < 64; o <<= 1) lmax = fmaxf(lmax, __shfl_xor(lmax, o));
    if ((tid & 63) == 0) rtmp[tid >> 6] = lmax;
    __syncthreads();
    const float bmax = fmaxf(fmaxf(rtmp[0], rtmp[1]), fmaxf(rtmp[2], rtmp[3]));
    __syncthreads();
    float lsumv = 0.f;
    for (int j = tid; j < L_DIM; j += 256) {
      float pv = __expf(p_s[j] - bmax);
      p_s[j] = pv;
      lsumv += pv;
    }
#pragma unroll
    for (int o = 1; o < 64; o <<= 1) lsumv += __shfl_xor(lsumv, o);
    if ((tid & 63) == 0) rtmp[tid >> 6] = lsumv;
    __syncthreads();
    const float bsum = rtmp[0] + rtmp[1] + rtmp[2] + rtmp[3];
    const int g = tid >> 5, d = tid & 31;
    float a = 0.f;
    for (int j = g * 128; j < g * 128 + 128; ++j) {
      float v = bf2f(Vf[(((size_t)(vb + (j >> 5))) * 2 + (d >> 4)) * 512 +
                        (((j >> 3) & 3) * 16 + (d & 15)) * 8 + (j & 7)]);
      a = fmaf(p_s[j], v, a);
    }
    red[g][d] = a;
    __syncthreads();
    if (tid < D_DIM) {
      float acc = 0.f;
#pragma unroll
      for (int gg = 0; gg < 8; ++gg) acc += red[gg][tid];
      float qabs = 0.f;
#pragma unroll
      for (int dd = 0; dd < D_DIM; ++dd) qabs += fabsf(qsh[dd]);
      const float qmv = qabs > 0.f ? 1.f : 0.f;
      out[((size_t)b * L_DIM) * 256 + h * D_DIM + tid] =
          acc * (1.0f / bsum) * qmv * (float)imask[b * L_DIM];
    }
    return;
  }

  // ---------------- combine path ----------------
  const int qc = (int)blockIdx.x;
  const int nseg = (qc >> 2) + 1;
  const int w = tid >> 6;
  const int l = tid & 63;
  const int lg = l >> 4;
  const int lc = l & 15;
  const int qbase = qc * 64 + w * 16;
  const int qt = qbase >> 4;
  const int pslot = (b * H_DIM + h) * 16 + qc;
  const float* Ob = &Opart[(size_t)pslot * 8192];
  const float* mlb = &MLpart[(size_t)pslot * 512];

  // query mask (row = lc within this wave's qt tile)
  short8v qfrag = *(const short8v*)&Qf[((size_t)(fb + qt)) * 512 + l * 8];
  float qabs_l = 0.f;
#pragma unroll
  for (int j = 0; j < 8; ++j) qabs_l += fabsf(bf2f((ushort_t)qfrag[j]));
  qabs_l += __shfl_xor(qabs_l, 16);
  qabs_l += __shfl_xor(qabs_l, 32);
  const float qm = (qabs_l > 0.f) ? 1.f : 0.f;

  float ms[4][4], ls[4][4];  // [seg][r], statically indexed
#pragma unroll
  for (int s = 0; s < 4; ++s) {
    if (s < nseg) {
#pragma unroll
      for (int r = 0; r < 4; ++r) {
        ms[s][r] = mlb[s * 128 + w * 16 + lg * 4 + r];
        ls[s][r] = mlb[s * 128 + 64 + w * 16 + lg * 4 + r];
      }
    }
  }
  float M[4], L[4];
#pragma unroll
  for (int r = 0; r < 4; ++r) {
    float mm = ms[0][r];
#pragma unroll
    for (int s = 1; s < 4; ++s)
      if (s < nseg) mm = fmaxf(mm, ms[s][r]);
    M[r] = mm;
    L[r] = 0.f;
  }
  f32x4 O0 = {0.f, 0.f, 0.f, 0.f};
  f32x4 O1 = {0.f, 0.f, 0.f, 0.f};
#pragma unroll
  for (int s = 0; s < 4; ++s) {
    if (s < nseg) {
      f32x4 o0 = *(const f32x4*)&Ob[s * 2048 + tid * 8];
      f32x4 o1 = *(const f32x4*)&Ob[s * 2048 + tid * 8 + 4];
#pragma unroll
      for (int r = 0; r < 4; ++r) {
        const float f = __expf(ms[s][r] - M[r]);
        L[r] += ls[s][r] * f;
        O0[r] += o0[r] * f;
        O1[r] += o1[r] * f;
      }
    }
  }

#pragma unroll
  for (int r = 0; r < 4; ++r) {
    const int rr = lg * 4 + r;
    const int qrow = qbase + rr;
    float qmr = __shfl(qm, rr);
    float im = (float)imask[b * L_DIM + qrow];
    float scl = (1.0f / L[r]) * qmr * im;
    if (qrow != 0) {
      float* op = &out[((size_t)(b * L_DIM + qrow)) * 256 + h * D_DIM];
      op[lc] = O0[r] * scl;
      op[16 + lc] = O1[r] * scl;
    }
  }
}

// ---------------------------------------------------------------------------
extern "C" void kernel_launch(void* const* d_in, const int* in_sizes, int n_in,
                              void* d_out, int out_size, void* d_ws, size_t ws_size,
                              hipStream_t stream) {
  (void)in_sizes; (void)n_in; (void)out_size; (void)ws_size;
  const float* query = (const float*)d_in[0];
  const float* input = (const float*)d_in[1];
  const int* imask = (const int*)d_in[2];
  const float* t_in = (const float*)d_in[3];
  const float* Wq = (const float*)d_in[5];
  const float* Wk = (const float*)d_in[6];
  const float* Wv = (const float*)d_in[7];
  const float* pW1 = (const float*)d_in[8],  *pb1 = (const float*)d_in[9];
  const float* pW2 = (const float*)d_in[10], *pb2 = (const float*)d_in[11];
  const float* sW1 = (const float*)d_in[12], *sb1 = (const float*)d_in[13];
  const float* sW2 = (const float*)d_in[14], *sb2 = (const float*)d_in[15];
  const float* bW1 = (const float*)d_in[16], *bb1 = (const float*)d_in[17];
  const float* bW2 = (const float*)d_in[18], *bb2 = (const float*)d_in[19];
  float* out = (float*)d_out;

  const int M = B_DIM * L_DIM;  // 4096
  char* p = (char*)d_ws;
  ushort_t* Qf = (ushort_t*)p;  p += (size_t)M * 256 * 2;   // 2 MB
  ushort_t* Kf = (ushort_t*)p;  p += (size_t)M * 256 * 2;
  ushort_t* Vf = (ushort_t*)p;  p += (size_t)M * 256 * 2;
  ushort_t* Xfq = (ushort_t*)p; p += (size_t)M * 256 * 2;
  ushort_t* Xfi = (ushort_t*)p; p += (size_t)M * 256 * 2;
  ushort_t* Wfb = (ushort_t*)p; p += (size_t)3 * 256 * 256 * 2;
  float* ptf = (float*)p;       p += (size_t)M * TD * 4;
  float* sg = (float*)p;        p += (size_t)M * TD * 4;
  float* bs = (float*)p;        p += (size_t)M * TD * 4;
  float* tkbuf = (float*)p;     p += (size_t)B_DIM * NTILES_TOT * 512 * 4;  // 8.65 MB
  float* Opart = (float*)p;     p += (size_t)512 * 8192 * 4;                // 16.8 MB
  float* MLpart = (float*)p;    // 1 MB

  prep_kernel<<<1632, 256, 0, stream>>>(
      t_in, pW1, pb1, pW2, pb2, sW1, sb1, sW2, sb2, bW1, bb1, bW2, bb2,
      ptf, sg, bs, query, input, Xfq, Xfi, Wq, Wk, Wv, Wfb);
  work_kernel<<<384 + B_DIM * NTILES_TOT, 256, 0, stream>>>(
      Xfq, Xfi, Wfb, Qf, Kf, Vf, ptf, sg, bs, t_in, tkbuf);
  attn_partial_kernel<<<dim3(40, H_DIM, B_DIM), 256, 0, stream>>>(
      Qf, Kf, Vf, tkbuf, Opart, MLpart);
  combine_row0_kernel<<<dim3(17, H_DIM, B_DIM), 256, 0, stream>>>(
      Qf, Kf, Vf, tkbuf, Opart, MLpart, imask, out);
}